// Round 11
// baseline (281.052 us; speedup 1.0000x reference)
//
#include <hip/hip_runtime.h>
#include <stdint.h>

// B=4, N=2048, C=1024, H=16, D=64. Inputs/outputs are fp32 (proven: bf16-read
// rounds NaN'd; dual-variant rounds passed via the fp32 path). bf16 MFMA inside.
//
// v12 = v11 (272.1us) + attn XCD-locality grid swap + T5 setprio:
//  - attn grid (bh, p): wgid = p*64 + bh, 64%8==0 -> XCD = bh%8. All 16 blocks
//    of a head land on ONE XCD; 8 heads x 512KB K/VT = 4MB = one L2. Targets
//    the 3x over-fetch (FETCH 143MB vs 48MB ideal) -> prefetch sees L2 (~200cy)
//    not HBM (~900cy). v4 measured this exact effect (135->34MB).
//  - setprio(1) around attn MFMA clusters (m191: +4-7% attn, independent-block
//    structure). Bank-conflict counter rise analyzed: b64 V-reads are at the
//    512B structural floor (2 lanes/bank/phase) -> noise, not a lever.
//  - attn: lane-local k-slot map kv=kk*32+(j>=4)*16+quad*4+(j&3); aP packs with
//    NO cross-lane ops; B-frag = two ds_read_b64 from VT with same map.
//  - GEMMs: BK=64 m97 + XOR swizzle (v9-verified math), ascending-k accum.
//
// 5 launches: prep(cvt+tWqkv+tWproj) -> GEMM1(routed QKV, Q pre-scaled)
//             -> vtrans -> attn -> GEMM2(+bias).
// Memory map (u16 elems):
//  ws (64 MiB): q@0, k@8388608, v@16777216 (dead after vtrans),
//               attn_ws@16777216 (over v), wqkvT@25165824, wprojT@28311552.
//  d_out (32 MiB): xbf (dead after GEMM1) -> vt@0 (dead after attn) -> output.

typedef short s16x8 __attribute__((ext_vector_type(8)));
typedef short s16x4 __attribute__((ext_vector_type(4)));
typedef float f32x4 __attribute__((ext_vector_type(4)));
typedef unsigned int u32;

__device__ __forceinline__ uint16_t f2bf(float f) {
  union { float f; uint32_t u; } v; v.f = f;
  uint32_t r = v.u + 0x7fffu + ((v.u >> 16) & 1u);  // RNE
  return (uint16_t)(r >> 16);
}

__device__ __forceinline__ u32 cvt_pk_bf16(float lo, float hi) {
  u32 r;
  asm("v_cvt_pk_bf16_f32 %0, %1, %2" : "=v"(r) : "v"(lo), "v"(hi));
  return r;
}

__device__ __forceinline__ s16x8 pack4(u32 w0, u32 w1, u32 w2, u32 w3) {
  union { u32 u[4]; s16x8 v; } t;
  t.u[0] = w0; t.u[1] = w1; t.u[2] = w2; t.u[3] = w3;
  return t.v;
}

__device__ __forceinline__ s16x8 pack2h(s16x4 a, s16x4 b) {
  union { s16x4 h[2]; s16x8 v; } t;
  t.h[0] = a; t.h[1] = b;
  return t.v;
}

// async 16B global->LDS; dest = wave-uniform base + lane*16 (m97-verified form)
#define GLOAD_LDS16(g, l)                                            \
  __builtin_amdgcn_global_load_lds(                                  \
      (const __attribute__((address_space(1))) void*)(g),            \
      (__attribute__((address_space(3))) void*)(l), 16, 0, 0)

// ---------------- fused prep: cvt(x->bf16) + transpose Wqkv + transpose Wproj ----------------
__device__ __forceinline__ void transpose32_body(
    const float* __restrict__ src, uint16_t* __restrict__ dst,
    int R, int C, int bx32, int by32, uint16_t (*tile)[33], int tid) {
  const int tx = tid & 31, ty = tid >> 5;
#pragma unroll
  for (int i = 0; i < 32; i += 8)
    tile[ty + i][tx] = f2bf(src[(size_t)(by32 + ty + i) * C + bx32 + tx]);
  __syncthreads();
#pragma unroll
  for (int i = 0; i < 32; i += 8)
    dst[(size_t)(bx32 + ty + i) * R + by32 + tx] = tile[tx][ty + i];
}

__global__ __launch_bounds__(256) void prep_kernel(
    const float* __restrict__ x, uint16_t* __restrict__ xbf,
    const float* __restrict__ Wqkv, uint16_t* __restrict__ wqkvT,
    const float* __restrict__ Wproj, uint16_t* __restrict__ wprojT) {
  __shared__ uint16_t tile[32][33];
  const int bid = blockIdx.x;  // branch is block-uniform
  if (bid < 4096) {
    const int i = bid * 256 + threadIdx.x;  // 8,388,608 elems / 8 per thread
    const f32x4 a = ((const f32x4*)x)[2 * i];
    const f32x4 b = ((const f32x4*)x)[2 * i + 1];
    s16x8 r;
    r[0] = (short)f2bf(a[0]); r[1] = (short)f2bf(a[1]);
    r[2] = (short)f2bf(a[2]); r[3] = (short)f2bf(a[3]);
    r[4] = (short)f2bf(b[0]); r[5] = (short)f2bf(b[1]);
    r[6] = (short)f2bf(b[2]); r[7] = (short)f2bf(b[3]);
    ((s16x8*)xbf)[i] = r;
  } else if (bid < 4096 + 3072) {
    const int t = bid - 4096;  // Wqkv [1024][3072] -> [3072][1024]
    transpose32_body(Wqkv, wqkvT, 1024, 3072, (t % 96) * 32, (t / 96) * 32,
                     tile, threadIdx.x);
  } else {
    const int t = bid - 7168;  // Wproj [1024][1024] -> [1024][1024]^T
    transpose32_body(Wproj, wprojT, 1024, 1024, (t & 31) * 32, (t >> 5) * 32,
                     tile, threadIdx.x);
  }
}

// ---------------- per-head V transpose: [bh][2048][64] -> [bh][64][2048] ----------------
__global__ __launch_bounds__(256) void vtrans_kernel(
    const uint16_t* __restrict__ src, uint16_t* __restrict__ dst) {
  const int bh = blockIdx.y >> 1, dhalf = blockIdx.y & 1;
  const int n0 = blockIdx.x * 32, d0 = dhalf * 32;
  const uint16_t* sb = src + (size_t)bh * 131072;
  uint16_t* db = dst + (size_t)bh * 131072;
  __shared__ uint16_t tile[32][33];
  const int tx = threadIdx.x & 31, ty = threadIdx.x >> 5;
#pragma unroll
  for (int i = 0; i < 32; i += 8)
    tile[ty + i][tx] = sb[(size_t)(n0 + ty + i) * 64 + d0 + tx];
  __syncthreads();
#pragma unroll
  for (int i = 0; i < 32; i += 8)
    db[(size_t)(d0 + ty + i) * 2048 + n0 + tx] = tile[tx][ty + i];
}

// ---------------- GEMM (m97 + BK=64 + XOR swizzle): C = A @ Bt^T ----------------
// 128x128 tile, BK=64, 4 waves 64x64. Linear gload_lds dest + pre-XOR'd global
// source chunk; reads apply the same XOR (lane-const) -> conflict-free (v9-
// verified math). Ascending-k accumulation: bit-identical to BK=32 version.
template <bool ROUTE>
__global__ __launch_bounds__(256) void gemm_bt_kernel(
    const uint16_t* __restrict__ A, const uint16_t* __restrict__ Bt,
    float* __restrict__ Cout,
    uint16_t* __restrict__ rq, uint16_t* __restrict__ rk, uint16_t* __restrict__ rv,
    const float* __restrict__ bias, int M, int N, int K) {
  __shared__ uint16_t sA[128 * 64];
  __shared__ uint16_t sB[128 * 64];
  const int tid = threadIdx.x;
  const int lane = tid & 63, w = tid >> 6;
  const int l15 = lane & 15, quad = lane >> 4;
  const int row0 = blockIdx.y * 128, col0 = blockIdx.x * 128;
  const int wm = (w >> 1) * 64, wn = (w & 1) * 64;

  f32x4 acc[4][4];
#pragma unroll
  for (int i = 0; i < 4; ++i)
#pragma unroll
    for (int j = 0; j < 4; ++j)
#pragma unroll
      for (int e = 0; e < 4; ++e) acc[i][j][e] = 0.0f;

  // read-side swizzled chunk offsets (lane-constant): phys = logical ^ (row&7)
  const int sx = l15 & 7;
  const int ok[2] = {((0 * 4 + quad) ^ sx) * 8, ((1 * 4 + quad) ^ sx) * 8};

  for (int k0 = 0; k0 < K; k0 += 64) {
    __syncthreads();
#pragma unroll
    for (int i = 0; i < 4; ++i) {
      const int cbase = i * 256 + w * 64;  // wave-uniform
      const int c = cbase + lane;
      const int r = c >> 3;                       // row 0..127
      const int kc = ((c & 7) ^ (r & 7)) * 8;     // pre-swizzled source chunk
      GLOAD_LDS16(A + (size_t)(row0 + r) * K + k0 + kc, sA + cbase * 8);
      GLOAD_LDS16(Bt + (size_t)(col0 + r) * K + k0 + kc, sB + cbase * 8);
    }
    __syncthreads();

#pragma unroll
    for (int kk = 0; kk < 2; ++kk) {
      s16x8 aF[4], bF[4];
#pragma unroll
      for (int mt = 0; mt < 4; ++mt)
        aF[mt] = *(const s16x8*)(sA + (wm + mt * 16 + l15) * 64 + ok[kk]);
#pragma unroll
      for (int nt = 0; nt < 4; ++nt)
        bF[nt] = *(const s16x8*)(sB + (wn + nt * 16 + l15) * 64 + ok[kk]);
#pragma unroll
      for (int mt = 0; mt < 4; ++mt)
#pragma unroll
        for (int nt = 0; nt < 4; ++nt)
          acc[mt][nt] = __builtin_amdgcn_mfma_f32_16x16x32_bf16(aF[mt], bF[nt], acc[mt][nt], 0, 0, 0);
    }
  }

  if (ROUTE) {
    // col = which*1024 + h*64 + d -> dst[bh][n][64] (bf16)
    const int which = col0 >> 10;  // block-uniform (1024 % 128 == 0)
    uint16_t* dst = (which == 0) ? rq : ((which == 1) ? rk : rv);
    // Q pre-scaled by log2(e)/sqrt(D): folds softmax scale into the logits.
    const float qs = (which == 0) ? 0.18033688011112042f : 1.0f;
#pragma unroll
    for (int mt = 0; mt < 4; ++mt) {
#pragma unroll
      for (int nt = 0; nt < 4; ++nt) {
        const int colg0 = col0 + wn + nt * 16;
        const int h = (colg0 >> 6) & 15, d0 = colg0 & 63;
#pragma unroll
        for (int i = 0; i < 4; ++i) {
          const int rowg = row0 + wm + mt * 16 + quad * 4 + i;
          const int bh = ((rowg >> 11) << 4) + h, n = rowg & 2047;
          dst[(size_t)bh * 131072 + (size_t)n * 64 + d0 + l15] = f2bf(acc[mt][nt][i] * qs);
        }
      }
    }
  } else {
#pragma unroll
    for (int mt = 0; mt < 4; ++mt) {
#pragma unroll
      for (int nt = 0; nt < 4; ++nt) {
        const int colg = col0 + wn + nt * 16 + l15;
        const float bv = bias[colg];
#pragma unroll
        for (int i = 0; i < 4; ++i) {
          const int rowg = row0 + wm + mt * 16 + quad * 4 + i;
          Cout[(size_t)rowg * N + colg] = acc[mt][nt][i] + bv;
        }
      }
    }
  }
}

// ---------------- Flash attention, paired q-tiles, pipelined H chain ----------------
// Grid (bh, p): wgid = p*64 + bh -> XCD = bh%8 (linear dispatch). All 16 blocks
// of a head share one XCD's L2; 8 heads x 512KB K/VT = 4MB = one L2.
// Block handles q-tiles p and 31-p: constant 33 tile-computes/block.
// Q,K: [bh][n][64] (Q pre-scaled); VT: [bh][64][2048]. 4 waves x 16 q-rows/tile.
// Swapped QK^T: S^T = mfma(K_frag, Q_frag) -> lane (l15,quad) holds
// P[q=w*16+l15][kv=nt*16+quad*4+i]. Lane-local k-slot map for PV:
// slot(quad,j) -> kv = kk*32 + (j>=4)*16 + quad*4 + (j&3), so
// aP = pack4(lo0,hi0,lo1,hi1) with NO cross-lane ops; B-frag = two ds_read_b64
// from VT rows with the same map. Schedule per iter t: [stage regs->buf(t&1);
// prefetch t+1; finishH(t-1) from bufs^1] | barrier | [QK_H(t); L tile].
// Row-sum l via mfma(aP, ones) (slot-map-invariant): lacc[i] = row quad*4+i.
__global__ __launch_bounds__(256) void attn_kernel(
    const uint16_t* __restrict__ q_ws, const uint16_t* __restrict__ k_ws,
    const uint16_t* __restrict__ vt_ws, uint16_t* __restrict__ out) {
  const int bh = blockIdx.x;  // 0..63 -> XCD = bh % 8
  const int p = blockIdx.y;   // 0..15
  const int b = bh >> 4, h = bh & 15;
  const int q0L = p * 64, q0H = (31 - p) * 64;
  const int tid = threadIdx.x;
  const int lane = tid & 63, w = tid >> 6;
  const int l15 = lane & 15, quad = lane >> 4;

  const uint16_t* qb = q_ws + (size_t)bh * 131072;
  const uint16_t* kb = k_ws + (size_t)bh * 131072;
  const uint16_t* vtb = vt_ws + (size_t)bh * 131072;

  __shared__ uint16_t sK[2][64 * 72];  // [buf][kv][d], pad 72
  __shared__ uint16_t sV[2][64 * 72];  // [buf][d][kv], pad 72

  const int qrowL = q0L + w * 16 + l15;
  const int qrowH = q0H + w * 16 + l15;
  const s16x8 aQL0 = *(const s16x8*)(qb + (size_t)qrowL * 64 + quad * 8);
  const s16x8 aQL1 = *(const s16x8*)(qb + (size_t)qrowL * 64 + 32 + quad * 8);
  const s16x8 aQH0 = *(const s16x8*)(qb + (size_t)qrowH * 64 + quad * 8);
  const s16x8 aQH1 = *(const s16x8*)(qb + (size_t)qrowH * 64 + 32 + quad * 8);

  f32x4 oL[4], oH[4], laccL, laccH;
#pragma unroll
  for (int e = 0; e < 4; ++e) { laccL[e] = 0.0f; laccH[e] = 0.0f; }
#pragma unroll
  for (int i = 0; i < 4; ++i)
#pragma unroll
    for (int e = 0; e < 4; ++e) { oL[i][e] = 0.0f; oH[i][e] = 0.0f; }

  s16x8 bOnes;
#pragma unroll
  for (int j = 0; j < 8; ++j) bOnes[j] = (short)0x3F80;  // bf16 1.0

  const int vr = tid >> 2, dc = (tid & 3) * 16;
  s16x8 rk0 = *(const s16x8*)(kb + (size_t)vr * 64 + dc);
  s16x8 rk1 = *(const s16x8*)(kb + (size_t)vr * 64 + dc + 8);
  s16x8 rv0 = *(const s16x8*)(vtb + (size_t)vr * 2048 + dc);
  s16x8 rv1 = *(const s16x8*)(vtb + (size_t)vr * 2048 + dc + 8);

  const int qrel = w * 16 + l15;  // q index within 64-row tile

  // QK^T for one q-tile: 8 MFMA, result into s[4] (kept in VGPRs).
  auto qkt = [&](const s16x8& a0, const s16x8& a1, const uint16_t* sKb,
                 f32x4 (&s)[4]) {
    __builtin_amdgcn_s_setprio(1);
#pragma unroll
    for (int nt = 0; nt < 4; ++nt) {
      f32x4 z;
#pragma unroll
      for (int e = 0; e < 4; ++e) z[e] = 0.0f;
      const s16x8 bK0 = *(const s16x8*)(sKb + (nt * 16 + l15) * 72 + quad * 8);
      const s16x8 bK1 = *(const s16x8*)(sKb + (nt * 16 + l15) * 72 + 32 + quad * 8);
      // swapped operands: A=K rows (kv), B=Q row -> C[kv][q], col q = l15
      s[nt] = __builtin_amdgcn_mfma_f32_16x16x32_bf16(bK0, a0, z, 0, 0, 0);
      s[nt] = __builtin_amdgcn_mfma_f32_16x16x32_bf16(bK1, a1, s[nt], 0, 0, 0);
    }
    __builtin_amdgcn_s_setprio(0);
  };

  // softmax finish (P = exp2(s), raw v_exp_f32) + lane-local pack + lacc + PV.
  // k-slot map: slot(quad,j) -> kv = kk*32 + (j>=4)*16 + quad*4 + (j&3).
  auto finish = [&](const f32x4 (&s)[4], bool diag, f32x4* o, f32x4& lacc,
                    const uint16_t* sVb) {
#pragma unroll
    for (int kk = 0; kk < 2; ++kk) {
      u32 wlo[2], whi[2];
#pragma unroll
      for (int t2 = 0; t2 < 2; ++t2) {
        const f32x4& sv = s[2 * kk + t2];
        float pp[4];
        if (diag) {
          const int nt = 2 * kk + t2;
#pragma unroll
          for (int i = 0; i < 4; ++i) {
            const int kv = nt * 16 + quad * 4 + i;
            pp[i] = (kv > qrel) ? 0.0f : __builtin_amdgcn_exp2f(sv[i]);
          }
        } else {
#pragma unroll
          for (int i = 0; i < 4; ++i) pp[i] = __builtin_amdgcn_exp2f(sv[i]);
        }
        wlo[t2] = cvt_pk_bf16(pp[0], pp[1]);  // kv +0,+1
        whi[t2] = cvt_pk_bf16(pp[2], pp[3]);  // kv +2,+3
      }
      // lane-local A-frag: j0..3 = nt=2kk (kv=kk*32+quad*4+j),
      //                    j4..7 = nt=2kk+1 (kv=kk*32+16+quad*4+j)
      const s16x8 aP = pack4(wlo[0], whi[0], wlo[1], whi[1]);
      __builtin_amdgcn_s_setprio(1);
      // row-sum l via matrix pipe (ones operand: slot-map-invariant)
      lacc = __builtin_amdgcn_mfma_f32_16x16x32_bf16(aP, bOnes, lacc, 0, 0, 0);
#pragma unroll
      for (int dblk = 0; dblk < 4; ++dblk) {
        const uint16_t* vrow = sVb + (dblk * 16 + l15) * 72 + kk * 32 + quad * 4;
        const s16x4 b0 = *(const s16x4*)(vrow);        // kv kk*32+quad*4+0..3
        const s16x4 b1 = *(const s16x4*)(vrow + 16);   // kv kk*32+16+quad*4+0..3
        const s16x8 bV = pack2h(b0, b1);
        o[dblk] = __builtin_amdgcn_mfma_f32_16x16x32_bf16(aP, bV, o[dblk], 0, 0, 0);
      }
      __builtin_amdgcn_s_setprio(0);
    }
  };

  const int TH = q0H >> 6;  // last H tile (diag), = 31-p >= 16
  const int TL = q0L >> 6;  // last L tile (diag), = p
  f32x4 sHp[4];             // carried QK^T(H) result for the pipeline

  for (int t = 0; t <= TH; ++t) {
    const int buf = t & 1;
    uint16_t* sKb = sK[buf];
    uint16_t* sVb = sV[buf];
    // stage current tile's K/V (regs loaded prev iter) -> LDS buf
    *(s16x8*)(sKb + vr * 72 + dc) = rk0;
    *(s16x8*)(sKb + vr * 72 + dc + 8) = rk1;
    *(s16x8*)(sVb + vr * 72 + dc) = rv0;
    *(s16x8*)(sVb + vr * 72 + dc + 8) = rv1;
    // prefetch next tile
    if (t < TH) {
      const int kvn = (t + 1) << 6;
      rk0 = *(const s16x8*)(kb + (size_t)(kvn + vr) * 64 + dc);
      rk1 = *(const s16x8*)(kb + (size_t)(kvn + vr) * 64 + dc + 8);
      rv0 = *(const s16x8*)(vtb + (size_t)vr * 2048 + kvn + dc);
      rv1 = *(const s16x8*)(vtb + (size_t)vr * 2048 + kvn + dc + 8);
    }
    // finish previous H tile (never diag: diag H == TH handled in epilogue).
    // Reads sV[buf^1]; safe pre-barrier (all waves complete these reads before
    // the next barrier, which precedes any overwrite of that buffer).
    if (t >= 1) finish(sHp, false, oH, laccH, sV[buf ^ 1]);
    __syncthreads();
    // QK^T current H tile (pipelined into next iteration's finish)
    qkt(aQH0, aQH1, sKb, sHp);
    // L tile fully in-iteration (co-runs with H's phases)
    if (t <= TL) {
      f32x4 sLt[4];
      qkt(aQL0, aQL1, sKb, sLt);
      finish(sLt, t == TL, oL, laccL, sVb);
    }
  }
  finish(sHp, true, oH, laccH, sV[TH & 1]);  // epilogue: diag H tile

  const size_t obase = (size_t)b * 2048 * 1024 + (size_t)h * 64;
  auto epi = [&](f32x4* o, const f32x4& lacc, int q0) {
#pragma unroll
    for (int i = 0; i < 4; ++i) {
      const float invi = 1.0f / lacc[i];  // sum for q-row quad*4+i (C layout)
      const int row = q0 + w * 16 + quad * 4 + i;
#pragma unroll
      for (int dblk = 0; dblk < 4; ++dblk)
        out[obase + (size_t)row * 1024 + dblk * 16 + l15] = f2bf(o[dblk][i] * invi);
    }
  };
  epi(oH, laccH, q0H);
  epi(oL, laccL, q0L);
}

extern "C" void kernel_launch(void* const* d_in, const int* in_sizes, int n_in,
                              void* d_out, int out_size, void* d_ws, size_t ws_size,
                              hipStream_t stream) {
  (void)in_sizes; (void)n_in; (void)out_size; (void)ws_size;
  const float* x     = (const float*)d_in[0];
  // d_in[1] = attn_mask: exactly causal, applied analytically
  const float* Wqkv  = (const float*)d_in[2];
  const float* Wproj = (const float*)d_in[3];
  const float* bproj = (const float*)d_in[4];
  float* outp = (float*)d_out;

  uint16_t* ws      = (uint16_t*)d_ws;
  uint16_t* q_ws    = ws;                        // [64][2048][64]
  uint16_t* k_ws    = ws + (size_t)8388608;
  uint16_t* v_ws    = ws + (size_t)16777216;     // dead after vtrans
  uint16_t* attn_ws = ws + (size_t)16777216;     // written by attn (v dead)
  uint16_t* wqkvT   = ws + (size_t)25165824;     // 3.1M u16, GEMM1 B operand
  uint16_t* wprojT  = ws + (size_t)28311552;     // 1.0M u16, written in prep
  uint16_t* xbf     = (uint16_t*)d_out;          // d_out scratch; dead after GEMM1
  uint16_t* vt_ws   = (uint16_t*)d_out;          // vt over dead xbf (8.4M u16)

  // prep: blocks [0,4096) cvt, [4096,7168) tWqkv, [7168,8192) tWproj
  prep_kernel<<<8192, 256, 0, stream>>>(x, xbf, Wqkv, wqkvT, Wproj, wprojT);
  gemm_bt_kernel<true><<<dim3(24, 64), 256, 0, stream>>>(
      xbf, wqkvT, nullptr, q_ws, k_ws, v_ws, nullptr, 8192, 3072, 1024);
  vtrans_kernel<<<dim3(64, 128), 256, 0, stream>>>(v_ws, vt_ws);
  attn_kernel<<<dim3(64, 16), 256, 0, stream>>>(q_ws, k_ws, vt_ws, attn_ws);
  gemm_bt_kernel<false><<<dim3(8, 64), 256, 0, stream>>>(
      attn_ws, wprojT, outp, nullptr, nullptr, nullptr, bproj, 8192, 1024, 1024);
}

// Round 12
// 271.377 us; speedup vs baseline: 1.0357x; 1.0357x over previous
//
#include <hip/hip_runtime.h>
#include <stdint.h>

// B=4, N=2048, C=1024, H=16, D=64. Inputs/outputs are fp32 (proven: bf16-read
// rounds NaN'd; dual-variant rounds passed via the fp32 path). bf16 MFMA inside.
//
// v13 = v11 (272.1us best) + attn {L-chain pipelining, XOR-swizzled unpadded LDS}:
//  - v12 post-mortem: XCD grid swap cut FETCH 143->35MB but SLOWED attn (+4.4us)
//    -> over-fetch was not critical-path; one-XCD L2 slice serialized; setprio
//    in 4-wave barrier-locked blocks = m190 lockstep regime (negative). Both
//    reverted: grid (p,bh), no setprio.
//  - L chain now pipelined like H: per iter, {finish_H(t-1), finish_L(t-1)}
//    pre-barrier || {qkt_H(t), qkt_L(t)} post-barrier - 4 independent clusters.
//    L diag finish always in-loop (TL+1 <= TH since p<=15 < 16 <= 31-p).
//  - sK/sV: no pad, 8-elem-chunk XOR swizzle phys = chunk ^ (row&7). Every
//    staging write is one whole 16B chunk -> write/read swizzle symmetric.
//    Bank uniformity at structural floor verified for stage-writes, b128
//    K-reads, b64 V-reads. LDS 36864 -> 32768 B -> 5 blocks/CU (if VGPR<=102).
//  - attn core: swapped QK^T; lane-local k-slot map kv=kk*32+(j>=4)*16+quad*4+
//    (j&3) (aP packs with no cross-lane ops); raw v_exp_f32; lacc=mfma(aP,ones).
//  - GEMMs: BK=64 m97 + XOR swizzle (v9-verified), ascending-k accum.
//
// 5 launches: prep(cvt+tWqkv+tWproj) -> GEMM1(routed QKV, Q pre-scaled)
//             -> vtrans -> attn -> GEMM2(+bias).
// Memory map (u16 elems):
//  ws (64 MiB): q@0, k@8388608, v@16777216 (dead after vtrans),
//               attn_ws@16777216 (over v), wqkvT@25165824, wprojT@28311552.
//  d_out (32 MiB): xbf (dead after GEMM1) -> vt@0 (dead after attn) -> output.

typedef short s16x8 __attribute__((ext_vector_type(8)));
typedef short s16x4 __attribute__((ext_vector_type(4)));
typedef float f32x4 __attribute__((ext_vector_type(4)));
typedef unsigned int u32;

__device__ __forceinline__ uint16_t f2bf(float f) {
  union { float f; uint32_t u; } v; v.f = f;
  uint32_t r = v.u + 0x7fffu + ((v.u >> 16) & 1u);  // RNE
  return (uint16_t)(r >> 16);
}

__device__ __forceinline__ u32 cvt_pk_bf16(float lo, float hi) {
  u32 r;
  asm("v_cvt_pk_bf16_f32 %0, %1, %2" : "=v"(r) : "v"(lo), "v"(hi));
  return r;
}

__device__ __forceinline__ s16x8 pack4(u32 w0, u32 w1, u32 w2, u32 w3) {
  union { u32 u[4]; s16x8 v; } t;
  t.u[0] = w0; t.u[1] = w1; t.u[2] = w2; t.u[3] = w3;
  return t.v;
}

__device__ __forceinline__ s16x8 pack2h(s16x4 a, s16x4 b) {
  union { s16x4 h[2]; s16x8 v; } t;
  t.h[0] = a; t.h[1] = b;
  return t.v;
}

// async 16B global->LDS; dest = wave-uniform base + lane*16 (m97-verified form)
#define GLOAD_LDS16(g, l)                                            \
  __builtin_amdgcn_global_load_lds(                                  \
      (const __attribute__((address_space(1))) void*)(g),            \
      (__attribute__((address_space(3))) void*)(l), 16, 0, 0)

// ---------------- fused prep: cvt(x->bf16) + transpose Wqkv + transpose Wproj ----------------
__device__ __forceinline__ void transpose32_body(
    const float* __restrict__ src, uint16_t* __restrict__ dst,
    int R, int C, int bx32, int by32, uint16_t (*tile)[33], int tid) {
  const int tx = tid & 31, ty = tid >> 5;
#pragma unroll
  for (int i = 0; i < 32; i += 8)
    tile[ty + i][tx] = f2bf(src[(size_t)(by32 + ty + i) * C + bx32 + tx]);
  __syncthreads();
#pragma unroll
  for (int i = 0; i < 32; i += 8)
    dst[(size_t)(bx32 + ty + i) * R + by32 + tx] = tile[tx][ty + i];
}

__global__ __launch_bounds__(256) void prep_kernel(
    const float* __restrict__ x, uint16_t* __restrict__ xbf,
    const float* __restrict__ Wqkv, uint16_t* __restrict__ wqkvT,
    const float* __restrict__ Wproj, uint16_t* __restrict__ wprojT) {
  __shared__ uint16_t tile[32][33];
  const int bid = blockIdx.x;  // branch is block-uniform
  if (bid < 4096) {
    const int i = bid * 256 + threadIdx.x;  // 8,388,608 elems / 8 per thread
    const f32x4 a = ((const f32x4*)x)[2 * i];
    const f32x4 b = ((const f32x4*)x)[2 * i + 1];
    s16x8 r;
    r[0] = (short)f2bf(a[0]); r[1] = (short)f2bf(a[1]);
    r[2] = (short)f2bf(a[2]); r[3] = (short)f2bf(a[3]);
    r[4] = (short)f2bf(b[0]); r[5] = (short)f2bf(b[1]);
    r[6] = (short)f2bf(b[2]); r[7] = (short)f2bf(b[3]);
    ((s16x8*)xbf)[i] = r;
  } else if (bid < 4096 + 3072) {
    const int t = bid - 4096;  // Wqkv [1024][3072] -> [3072][1024]
    transpose32_body(Wqkv, wqkvT, 1024, 3072, (t % 96) * 32, (t / 96) * 32,
                     tile, threadIdx.x);
  } else {
    const int t = bid - 7168;  // Wproj [1024][1024] -> [1024][1024]^T
    transpose32_body(Wproj, wprojT, 1024, 1024, (t & 31) * 32, (t >> 5) * 32,
                     tile, threadIdx.x);
  }
}

// ---------------- per-head V transpose: [bh][2048][64] -> [bh][64][2048] ----------------
__global__ __launch_bounds__(256) void vtrans_kernel(
    const uint16_t* __restrict__ src, uint16_t* __restrict__ dst) {
  const int bh = blockIdx.y >> 1, dhalf = blockIdx.y & 1;
  const int n0 = blockIdx.x * 32, d0 = dhalf * 32;
  const uint16_t* sb = src + (size_t)bh * 131072;
  uint16_t* db = dst + (size_t)bh * 131072;
  __shared__ uint16_t tile[32][33];
  const int tx = threadIdx.x & 31, ty = threadIdx.x >> 5;
#pragma unroll
  for (int i = 0; i < 32; i += 8)
    tile[ty + i][tx] = sb[(size_t)(n0 + ty + i) * 64 + d0 + tx];
  __syncthreads();
#pragma unroll
  for (int i = 0; i < 32; i += 8)
    db[(size_t)(d0 + ty + i) * 2048 + n0 + tx] = tile[tx][ty + i];
}

// ---------------- GEMM (m97 + BK=64 + XOR swizzle): C = A @ Bt^T ----------------
// 128x128 tile, BK=64, 4 waves 64x64. Linear gload_lds dest + pre-XOR'd global
// source chunk; reads apply the same XOR (lane-const) -> conflict-free (v9-
// verified math). Ascending-k accumulation: bit-identical to BK=32 version.
template <bool ROUTE>
__global__ __launch_bounds__(256) void gemm_bt_kernel(
    const uint16_t* __restrict__ A, const uint16_t* __restrict__ Bt,
    float* __restrict__ Cout,
    uint16_t* __restrict__ rq, uint16_t* __restrict__ rk, uint16_t* __restrict__ rv,
    const float* __restrict__ bias, int M, int N, int K) {
  __shared__ uint16_t sA[128 * 64];
  __shared__ uint16_t sB[128 * 64];
  const int tid = threadIdx.x;
  const int lane = tid & 63, w = tid >> 6;
  const int l15 = lane & 15, quad = lane >> 4;
  const int row0 = blockIdx.y * 128, col0 = blockIdx.x * 128;
  const int wm = (w >> 1) * 64, wn = (w & 1) * 64;

  f32x4 acc[4][4];
#pragma unroll
  for (int i = 0; i < 4; ++i)
#pragma unroll
    for (int j = 0; j < 4; ++j)
#pragma unroll
      for (int e = 0; e < 4; ++e) acc[i][j][e] = 0.0f;

  // read-side swizzled chunk offsets (lane-constant): phys = logical ^ (row&7)
  const int sx = l15 & 7;
  const int ok[2] = {((0 * 4 + quad) ^ sx) * 8, ((1 * 4 + quad) ^ sx) * 8};

  for (int k0 = 0; k0 < K; k0 += 64) {
    __syncthreads();
#pragma unroll
    for (int i = 0; i < 4; ++i) {
      const int cbase = i * 256 + w * 64;  // wave-uniform
      const int c = cbase + lane;
      const int r = c >> 3;                       // row 0..127
      const int kc = ((c & 7) ^ (r & 7)) * 8;     // pre-swizzled source chunk
      GLOAD_LDS16(A + (size_t)(row0 + r) * K + k0 + kc, sA + cbase * 8);
      GLOAD_LDS16(Bt + (size_t)(col0 + r) * K + k0 + kc, sB + cbase * 8);
    }
    __syncthreads();

#pragma unroll
    for (int kk = 0; kk < 2; ++kk) {
      s16x8 aF[4], bF[4];
#pragma unroll
      for (int mt = 0; mt < 4; ++mt)
        aF[mt] = *(const s16x8*)(sA + (wm + mt * 16 + l15) * 64 + ok[kk]);
#pragma unroll
      for (int nt = 0; nt < 4; ++nt)
        bF[nt] = *(const s16x8*)(sB + (wn + nt * 16 + l15) * 64 + ok[kk]);
#pragma unroll
      for (int mt = 0; mt < 4; ++mt)
#pragma unroll
        for (int nt = 0; nt < 4; ++nt)
          acc[mt][nt] = __builtin_amdgcn_mfma_f32_16x16x32_bf16(aF[mt], bF[nt], acc[mt][nt], 0, 0, 0);
    }
  }

  if (ROUTE) {
    // col = which*1024 + h*64 + d -> dst[bh][n][64] (bf16)
    const int which = col0 >> 10;  // block-uniform (1024 % 128 == 0)
    uint16_t* dst = (which == 0) ? rq : ((which == 1) ? rk : rv);
    // Q pre-scaled by log2(e)/sqrt(D): folds softmax scale into the logits.
    const float qs = (which == 0) ? 0.18033688011112042f : 1.0f;
#pragma unroll
    for (int mt = 0; mt < 4; ++mt) {
#pragma unroll
      for (int nt = 0; nt < 4; ++nt) {
        const int colg0 = col0 + wn + nt * 16;
        const int h = (colg0 >> 6) & 15, d0 = colg0 & 63;
#pragma unroll
        for (int i = 0; i < 4; ++i) {
          const int rowg = row0 + wm + mt * 16 + quad * 4 + i;
          const int bh = ((rowg >> 11) << 4) + h, n = rowg & 2047;
          dst[(size_t)bh * 131072 + (size_t)n * 64 + d0 + l15] = f2bf(acc[mt][nt][i] * qs);
        }
      }
    }
  } else {
#pragma unroll
    for (int mt = 0; mt < 4; ++mt) {
#pragma unroll
      for (int nt = 0; nt < 4; ++nt) {
        const int colg = col0 + wn + nt * 16 + l15;
        const float bv = bias[colg];
#pragma unroll
        for (int i = 0; i < 4; ++i) {
          const int rowg = row0 + wm + mt * 16 + quad * 4 + i;
          Cout[(size_t)rowg * N + colg] = acc[mt][nt][i] + bv;
        }
      }
    }
  }
}

// ---------------- Flash attention: both chains pipelined, swizzled LDS ----------------
// Grid (p, bh). Block handles q-tiles p and 31-p: constant 33 tile-computes.
// Q,K: [bh][n][64] (Q pre-scaled); VT: [bh][64][2048]. 4 waves x 16 q-rows/tile.
// Swapped QK^T: S^T = mfma(K_frag, Q_frag) -> lane (l15,quad) holds
// P[q=w*16+l15][kv=nt*16+quad*4+i]. Lane-local k-slot map for PV:
// slot(quad,j) -> kv = kk*32 + (j>=4)*16 + quad*4 + (j&3); aP packs with no
// cross-lane ops; B-frag = two ds_read_b64 from swizzled VT rows (same map).
// LDS: sK/sV [2][64*64] unpadded, 8-elem-chunk XOR swizzle phys=chunk^(row&7)
// (each staging write = one whole chunk; write/read symmetric; bank-uniform).
// Schedule per iter t: [stage buf(t&1); prefetch t+1; finish_H(t-1);
// finish_L(t-1)] | barrier | [qkt_H(t); qkt_L(t)]. L diag finish in-loop
// (TL+1 <= TH). Row-sum l via mfma(aP, ones): lacc[i] = row quad*4+i.
__global__ __launch_bounds__(256) void attn_kernel(
    const uint16_t* __restrict__ q_ws, const uint16_t* __restrict__ k_ws,
    const uint16_t* __restrict__ vt_ws, uint16_t* __restrict__ out) {
  const int p = blockIdx.x;  // 0..15
  const int bh = blockIdx.y;
  const int b = bh >> 4, h = bh & 15;
  const int q0L = p * 64, q0H = (31 - p) * 64;
  const int tid = threadIdx.x;
  const int lane = tid & 63, w = tid >> 6;
  const int l15 = lane & 15, quad = lane >> 4;

  const uint16_t* qb = q_ws + (size_t)bh * 131072;
  const uint16_t* kb = k_ws + (size_t)bh * 131072;
  const uint16_t* vtb = vt_ws + (size_t)bh * 131072;

  __shared__ uint16_t sK[2][64 * 64];  // [buf][row][chunk^(row&7)], no pad
  __shared__ uint16_t sV[2][64 * 64];

  const int qrowL = q0L + w * 16 + l15;
  const int qrowH = q0H + w * 16 + l15;
  const s16x8 aQL0 = *(const s16x8*)(qb + (size_t)qrowL * 64 + quad * 8);
  const s16x8 aQL1 = *(const s16x8*)(qb + (size_t)qrowL * 64 + 32 + quad * 8);
  const s16x8 aQH0 = *(const s16x8*)(qb + (size_t)qrowH * 64 + quad * 8);
  const s16x8 aQH1 = *(const s16x8*)(qb + (size_t)qrowH * 64 + 32 + quad * 8);

  f32x4 oL[4], oH[4], laccL, laccH;
#pragma unroll
  for (int e = 0; e < 4; ++e) { laccL[e] = 0.0f; laccH[e] = 0.0f; }
#pragma unroll
  for (int i = 0; i < 4; ++i)
#pragma unroll
    for (int e = 0; e < 4; ++e) { oL[i][e] = 0.0f; oH[i][e] = 0.0f; }

  s16x8 bOnes;
#pragma unroll
  for (int j = 0; j < 8; ++j) bOnes[j] = (short)0x3F80;  // bf16 1.0

  // staging geometry: thread owns row vr, chunks c0=2*(tid&3), c0+1 (16B each)
  const int vr = tid >> 2, dc = (tid & 3) * 16;
  const int wc0 = ((tid & 3) * 2 + 0) ^ (vr & 7);  // swizzled phys chunks
  const int wc1 = ((tid & 3) * 2 + 1) ^ (vr & 7);
  s16x8 rk0 = *(const s16x8*)(kb + (size_t)vr * 64 + dc);
  s16x8 rk1 = *(const s16x8*)(kb + (size_t)vr * 64 + dc + 8);
  s16x8 rv0 = *(const s16x8*)(vtb + (size_t)vr * 2048 + dc);
  s16x8 rv1 = *(const s16x8*)(vtb + (size_t)vr * 2048 + dc + 8);

  // read-side swizzled offsets (lane-constant), rows have (row&7) == (l15&7)
  const int sx = l15 & 7;
  const int okK0 = (quad ^ sx) * 8;        // K chunk quad
  const int okK1 = ((quad + 4) ^ sx) * 8;  // K chunk quad+4
  // V b64 reads: logical chunk kk*4 + (quad>>1) (+2 for upper), in-chunk (quad&1)*4
  const int ovA[2] = {((0 + (quad >> 1)) ^ sx) * 8 + (quad & 1) * 4,
                      ((4 + (quad >> 1)) ^ sx) * 8 + (quad & 1) * 4};
  const int ovB[2] = {((2 + (quad >> 1)) ^ sx) * 8 + (quad & 1) * 4,
                      ((6 + (quad >> 1)) ^ sx) * 8 + (quad & 1) * 4};

  const int qrel = w * 16 + l15;  // q index within 64-row tile

  // QK^T for one q-tile: 8 MFMA, result into s[4] (kept in VGPRs).
  auto qkt = [&](const s16x8& a0, const s16x8& a1, const uint16_t* sKb,
                 f32x4 (&s)[4]) {
#pragma unroll
    for (int nt = 0; nt < 4; ++nt) {
      f32x4 z;
#pragma unroll
      for (int e = 0; e < 4; ++e) z[e] = 0.0f;
      const s16x8 bK0 = *(const s16x8*)(sKb + (nt * 16 + l15) * 64 + okK0);
      const s16x8 bK1 = *(const s16x8*)(sKb + (nt * 16 + l15) * 64 + okK1);
      // swapped operands: A=K rows (kv), B=Q row -> C[kv][q], col q = l15
      s[nt] = __builtin_amdgcn_mfma_f32_16x16x32_bf16(bK0, a0, z, 0, 0, 0);
      s[nt] = __builtin_amdgcn_mfma_f32_16x16x32_bf16(bK1, a1, s[nt], 0, 0, 0);
    }
  };

  // softmax finish (P = exp2(s), raw v_exp_f32) + lane-local pack + lacc + PV.
  // k-slot map: slot(quad,j) -> kv = kk*32 + (j>=4)*16 + quad*4 + (j&3).
  auto finish = [&](const f32x4 (&s)[4], bool diag, f32x4* o, f32x4& lacc,
                    const uint16_t* sVb) {
#pragma unroll
    for (int kk = 0; kk < 2; ++kk) {
      u32 wlo[2], whi[2];
#pragma unroll
      for (int t2 = 0; t2 < 2; ++t2) {
        const f32x4& sv = s[2 * kk + t2];
        float pp[4];
        if (diag) {
          const int nt = 2 * kk + t2;
#pragma unroll
          for (int i = 0; i < 4; ++i) {
            const int kv = nt * 16 + quad * 4 + i;
            pp[i] = (kv > qrel) ? 0.0f : __builtin_amdgcn_exp2f(sv[i]);
          }
        } else {
#pragma unroll
          for (int i = 0; i < 4; ++i) pp[i] = __builtin_amdgcn_exp2f(sv[i]);
        }
        wlo[t2] = cvt_pk_bf16(pp[0], pp[1]);  // kv +0,+1
        whi[t2] = cvt_pk_bf16(pp[2], pp[3]);  // kv +2,+3
      }
      // lane-local A-frag: j0..3 = nt=2kk (kv=kk*32+quad*4+j),
      //                    j4..7 = nt=2kk+1 (kv=kk*32+16+quad*4+j)
      const s16x8 aP = pack4(wlo[0], whi[0], wlo[1], whi[1]);
      // row-sum l via matrix pipe (ones operand: slot-map-invariant)
      lacc = __builtin_amdgcn_mfma_f32_16x16x32_bf16(aP, bOnes, lacc, 0, 0, 0);
#pragma unroll
      for (int dblk = 0; dblk < 4; ++dblk) {
        const uint16_t* vrow = sVb + (dblk * 16 + l15) * 64;
        const s16x4 b0 = *(const s16x4*)(vrow + ovA[kk]);  // kv kk*32+quad*4+..
        const s16x4 b1 = *(const s16x4*)(vrow + ovB[kk]);  // kv kk*32+16+quad*4+..
        const s16x8 bV = pack2h(b0, b1);
        o[dblk] = __builtin_amdgcn_mfma_f32_16x16x32_bf16(aP, bV, o[dblk], 0, 0, 0);
      }
    }
  };

  const int TH = q0H >> 6;  // last H tile (diag), = 31-p >= 16
  const int TL = q0L >> 6;  // last L tile (diag), = p <= 15 < TH
  f32x4 sHp[4], sLp[4];     // carried QK^T results for both pipelines

  for (int t = 0; t <= TH; ++t) {
    const int buf = t & 1;
    uint16_t* sKb = sK[buf];
    uint16_t* sVb = sV[buf];
    // stage current tile's K/V (regs loaded prev iter) -> swizzled chunks
    *(s16x8*)(sKb + vr * 64 + wc0 * 8) = rk0;
    *(s16x8*)(sKb + vr * 64 + wc1 * 8) = rk1;
    *(s16x8*)(sVb + vr * 64 + wc0 * 8) = rv0;
    *(s16x8*)(sVb + vr * 64 + wc1 * 8) = rv1;
    // prefetch next tile
    if (t < TH) {
      const int kvn = (t + 1) << 6;
      rk0 = *(const s16x8*)(kb + (size_t)(kvn + vr) * 64 + dc);
      rk1 = *(const s16x8*)(kb + (size_t)(kvn + vr) * 64 + dc + 8);
      rv0 = *(const s16x8*)(vtb + (size_t)vr * 2048 + kvn + dc);
      rv1 = *(const s16x8*)(vtb + (size_t)vr * 2048 + kvn + dc + 8);
    }
    // finish previous tiles (read sV[buf^1] = tile t-1; safe pre-barrier:
    // all waves complete these reads before barrier t, which precedes the
    // overwrite of that buffer at iteration t+1).
    if (t >= 1) {
      finish(sHp, false, oH, laccH, sV[buf ^ 1]);  // H diag -> epilogue
      if (t - 1 <= TL) finish(sLp, (t - 1) == TL, oL, laccL, sV[buf ^ 1]);
    }
    __syncthreads();
    // QK^T current tiles (consumed by next iteration's finishes)
    qkt(aQH0, aQH1, sKb, sHp);
    if (t <= TL) qkt(aQL0, aQL1, sKb, sLp);
  }
  finish(sHp, true, oH, laccH, sV[TH & 1]);  // epilogue: diag H tile

  const size_t obase = (size_t)b * 2048 * 1024 + (size_t)h * 64;
  auto epi = [&](f32x4* o, const f32x4& lacc, int q0) {
#pragma unroll
    for (int i = 0; i < 4; ++i) {
      const float invi = 1.0f / lacc[i];  // sum for q-row quad*4+i (C layout)
      const int row = q0 + w * 16 + quad * 4 + i;
#pragma unroll
      for (int dblk = 0; dblk < 4; ++dblk)
        out[obase + (size_t)row * 1024 + dblk * 16 + l15] = f2bf(o[dblk][i] * invi);
    }
  };
  epi(oH, laccH, q0H);
  epi(oL, laccL, q0L);
}

extern "C" void kernel_launch(void* const* d_in, const int* in_sizes, int n_in,
                              void* d_out, int out_size, void* d_ws, size_t ws_size,
                              hipStream_t stream) {
  (void)in_sizes; (void)n_in; (void)out_size; (void)ws_size;
  const float* x     = (const float*)d_in[0];
  // d_in[1] = attn_mask: exactly causal, applied analytically
  const float* Wqkv  = (const float*)d_in[2];
  const float* Wproj = (const float*)d_in[3];
  const float* bproj = (const float*)d_in[4];
  float* outp = (float*)d_out;

  uint16_t* ws      = (uint16_t*)d_ws;
  uint16_t* q_ws    = ws;                        // [64][2048][64]
  uint16_t* k_ws    = ws + (size_t)8388608;
  uint16_t* v_ws    = ws + (size_t)16777216;     // dead after vtrans
  uint16_t* attn_ws = ws + (size_t)16777216;     // written by attn (v dead)
  uint16_t* wqkvT   = ws + (size_t)25165824;     // 3.1M u16, GEMM1 B operand
  uint16_t* wprojT  = ws + (size_t)28311552;     // 1.0M u16, written in prep
  uint16_t* xbf     = (uint16_t*)d_out;          // d_out scratch; dead after GEMM1
  uint16_t* vt_ws   = (uint16_t*)d_out;          // vt over dead xbf (8.4M u16)

  // prep: blocks [0,4096) cvt, [4096,7168) tWqkv, [7168,8192) tWproj
  prep_kernel<<<8192, 256, 0, stream>>>(x, xbf, Wqkv, wqkvT, Wproj, wprojT);
  gemm_bt_kernel<true><<<dim3(24, 64), 256, 0, stream>>>(
      xbf, wqkvT, nullptr, q_ws, k_ws, v_ws, nullptr, 8192, 3072, 1024);
  vtrans_kernel<<<dim3(64, 128), 256, 0, stream>>>(v_ws, vt_ws);
  attn_kernel<<<dim3(16, 64), 256, 0, stream>>>(q_ws, k_ws, vt_ws, attn_ws);
  gemm_bt_kernel<false><<<dim3(8, 64), 256, 0, stream>>>(
      attn_ws, wprojT, outp, nullptr, nullptr, nullptr, bproj, 8192, 1024, 1024);
}

// Round 13
// 267.072 us; speedup vs baseline: 1.0523x; 1.0161x over previous
//
#include <hip/hip_runtime.h>
#include <stdint.h>

// B=4, N=2048, C=1024, H=16, D=64. Inputs/outputs are fp32 (proven: bf16-read
// rounds NaN'd; dual-variant rounds passed via the fp32 path). bf16 MFMA inside.
//
// v14 = v13 (271.4us) minus the vtrans kernel and one dispatch boundary:
//  - GEMM1 writes VT directly: for V blocks (which==2) each wave's 64x64
//    quadrant = one head's full d x 64 consecutive n. Wave-local LDS transpose
//    (8KB slice of dead sA/sB, chunk-XOR swizzle phys=chunk^(d&7)): 16
//    ds_write_b64 + 8 ds_read_b128 + 8x16B global stores (FEWER instrs than
//    the 64 scalar u16 routing stores it replaces). Block-uniform barrier
//    before LDS reuse. cvt_pk(RNE) == f2bf(RNE): bit-identical V values.
//  - attn output -> q_ws in head layout (race-free: each block reads only its
//    own Q rows, hoisted at kernel start). gemm2 reads A head-layout:
//    aoff = b<<21 | h<<17 | n<<6 | d  (== attn's write addr bh*131072+n*64+d).
//  - 4 launches: prep -> GEMM1(Q,K routed + VT) -> attn -> gemm2(+bias).
//  - attn core unchanged from v13: both chains pipelined, swizzled unpadded
//    LDS, lane-local k-slot map, raw v_exp_f32, lacc via mfma(aP,ones).
//  - GEMMs: BK=64 m97 + XOR swizzle (v9-verified), ascending-k accumulation.
//
// Memory map (u16 elems):
//  ws (64 MiB): q@0 (attn overwrites with its output), k@8388608,
//               vt@16777216 (gemm1-written, live through attn),
//               wqkvT@25165824, wprojT@28311552.  (29.4M of 33.5M used)
//  d_out (32 MiB): xbf (bf16 x, dead after GEMM1) -> final fp32 output (GEMM2).

typedef short s16x8 __attribute__((ext_vector_type(8)));
typedef short s16x4 __attribute__((ext_vector_type(4)));
typedef float f32x4 __attribute__((ext_vector_type(4)));
typedef int i32x2 __attribute__((ext_vector_type(2)));
typedef unsigned int u32;

__device__ __forceinline__ uint16_t f2bf(float f) {
  union { float f; uint32_t u; } v; v.f = f;
  uint32_t r = v.u + 0x7fffu + ((v.u >> 16) & 1u);  // RNE
  return (uint16_t)(r >> 16);
}

__device__ __forceinline__ u32 cvt_pk_bf16(float lo, float hi) {
  u32 r;
  asm("v_cvt_pk_bf16_f32 %0, %1, %2" : "=v"(r) : "v"(lo), "v"(hi));
  return r;
}

__device__ __forceinline__ s16x8 pack4(u32 w0, u32 w1, u32 w2, u32 w3) {
  union { u32 u[4]; s16x8 v; } t;
  t.u[0] = w0; t.u[1] = w1; t.u[2] = w2; t.u[3] = w3;
  return t.v;
}

__device__ __forceinline__ s16x8 pack2h(s16x4 a, s16x4 b) {
  union { s16x4 h[2]; s16x8 v; } t;
  t.h[0] = a; t.h[1] = b;
  return t.v;
}

// async 16B global->LDS; dest = wave-uniform base + lane*16 (m97-verified form)
#define GLOAD_LDS16(g, l)                                            \
  __builtin_amdgcn_global_load_lds(                                  \
      (const __attribute__((address_space(1))) void*)(g),            \
      (__attribute__((address_space(3))) void*)(l), 16, 0, 0)

// ---------------- fused prep: cvt(x->bf16) + transpose Wqkv + transpose Wproj ----------------
__device__ __forceinline__ void transpose32_body(
    const float* __restrict__ src, uint16_t* __restrict__ dst,
    int R, int C, int bx32, int by32, uint16_t (*tile)[33], int tid) {
  const int tx = tid & 31, ty = tid >> 5;
#pragma unroll
  for (int i = 0; i < 32; i += 8)
    tile[ty + i][tx] = f2bf(src[(size_t)(by32 + ty + i) * C + bx32 + tx]);
  __syncthreads();
#pragma unroll
  for (int i = 0; i < 32; i += 8)
    dst[(size_t)(bx32 + ty + i) * R + by32 + tx] = tile[tx][ty + i];
}

__global__ __launch_bounds__(256) void prep_kernel(
    const float* __restrict__ x, uint16_t* __restrict__ xbf,
    const float* __restrict__ Wqkv, uint16_t* __restrict__ wqkvT,
    const float* __restrict__ Wproj, uint16_t* __restrict__ wprojT) {
  __shared__ uint16_t tile[32][33];
  const int bid = blockIdx.x;  // branch is block-uniform
  if (bid < 4096) {
    const int i = bid * 256 + threadIdx.x;  // 8,388,608 elems / 8 per thread
    const f32x4 a = ((const f32x4*)x)[2 * i];
    const f32x4 b = ((const f32x4*)x)[2 * i + 1];
    s16x8 r;
    r[0] = (short)f2bf(a[0]); r[1] = (short)f2bf(a[1]);
    r[2] = (short)f2bf(a[2]); r[3] = (short)f2bf(a[3]);
    r[4] = (short)f2bf(b[0]); r[5] = (short)f2bf(b[1]);
    r[6] = (short)f2bf(b[2]); r[7] = (short)f2bf(b[3]);
    ((s16x8*)xbf)[i] = r;
  } else if (bid < 4096 + 3072) {
    const int t = bid - 4096;  // Wqkv [1024][3072] -> [3072][1024]
    transpose32_body(Wqkv, wqkvT, 1024, 3072, (t % 96) * 32, (t / 96) * 32,
                     tile, threadIdx.x);
  } else {
    const int t = bid - 7168;  // Wproj [1024][1024] -> [1024][1024]^T
    transpose32_body(Wproj, wprojT, 1024, 1024, (t & 31) * 32, (t >> 5) * 32,
                     tile, threadIdx.x);
  }
}

// ---------------- GEMM1 (m97 BK=64 + swizzle): routes Q,K; writes VT directly ----------------
// C[8192,3072] = xbf @ wqkvT^T. Q pre-scaled by log2e/sqrt(D). For V blocks
// (which==2): per-wave 64x64 in-LDS transpose (chunk-XOR swizzle) -> vt[bh][d][n].
__global__ __launch_bounds__(256) void gemm1_kernel(
    const uint16_t* __restrict__ A, const uint16_t* __restrict__ Bt,
    uint16_t* __restrict__ rq, uint16_t* __restrict__ rk,
    uint16_t* __restrict__ vt) {
  constexpr int K = 1024;
  __shared__ uint16_t sA[128 * 64];
  __shared__ uint16_t sB[128 * 64];
  const int tid = threadIdx.x;
  const int lane = tid & 63, w = tid >> 6;
  const int l15 = lane & 15, quad = lane >> 4;
  const int row0 = blockIdx.y * 128, col0 = blockIdx.x * 128;
  const int wm = (w >> 1) * 64, wn = (w & 1) * 64;

  f32x4 acc[4][4];
#pragma unroll
  for (int i = 0; i < 4; ++i)
#pragma unroll
    for (int j = 0; j < 4; ++j)
#pragma unroll
      for (int e = 0; e < 4; ++e) acc[i][j][e] = 0.0f;

  // read-side swizzled chunk offsets (lane-constant): phys = logical ^ (row&7)
  const int sx = l15 & 7;
  const int ok[2] = {((0 * 4 + quad) ^ sx) * 8, ((1 * 4 + quad) ^ sx) * 8};

  for (int k0 = 0; k0 < K; k0 += 64) {
    __syncthreads();
#pragma unroll
    for (int i = 0; i < 4; ++i) {
      const int cbase = i * 256 + w * 64;  // wave-uniform
      const int c = cbase + lane;
      const int r = c >> 3;                       // row 0..127
      const int kc = ((c & 7) ^ (r & 7)) * 8;     // pre-swizzled source chunk
      GLOAD_LDS16(A + (size_t)(row0 + r) * K + k0 + kc, sA + cbase * 8);
      GLOAD_LDS16(Bt + (size_t)(col0 + r) * K + k0 + kc, sB + cbase * 8);
    }
    __syncthreads();

#pragma unroll
    for (int kk = 0; kk < 2; ++kk) {
      s16x8 aF[4], bF[4];
#pragma unroll
      for (int mt = 0; mt < 4; ++mt)
        aF[mt] = *(const s16x8*)(sA + (wm + mt * 16 + l15) * 64 + ok[kk]);
#pragma unroll
      for (int nt = 0; nt < 4; ++nt)
        bF[nt] = *(const s16x8*)(sB + (wn + nt * 16 + l15) * 64 + ok[kk]);
#pragma unroll
      for (int mt = 0; mt < 4; ++mt)
#pragma unroll
        for (int nt = 0; nt < 4; ++nt)
          acc[mt][nt] = __builtin_amdgcn_mfma_f32_16x16x32_bf16(aF[mt], bF[nt], acc[mt][nt], 0, 0, 0);
    }
  }

  const int which = col0 >> 10;  // block-uniform (1024 % 128 == 0)
  if (which == 2) {
    // ---- V: wave-local 64x64 transpose via dead sA/sB -> vt[bh][d][n] ----
    __syncthreads();  // all waves done reading sA/sB fragments
    uint16_t* tw = (w < 2) ? (sA + w * 4096) : (sB + (w - 2) * 4096);  // 8KB
    const int colg0 = col0 + wn;          // multiple of 64 -> one head's d
    const int h = (colg0 >> 6) & 15;
    const int rbase = row0 + wm;          // 64-row span, single b
    const int bq = rbase >> 11, n0 = rbase & 2047;
    const int bh = bq * 16 + h;
    // write acc transposed: T[d_local][n_local], chunk-XOR swizzled
    const int coff = quad >> 1;           // +mt*2 below
    const int boff = (quad & 1) * 4;      // elems within 8-elem chunk
#pragma unroll
    for (int mt = 0; mt < 4; ++mt) {
#pragma unroll
      for (int nt = 0; nt < 4; ++nt) {
        const int dloc = nt * 16 + l15;
        const int phys = (mt * 2 + coff) ^ (dloc & 7);
        i32x2 pr;
        pr[0] = (int)cvt_pk_bf16(acc[mt][nt][0], acc[mt][nt][1]);
        pr[1] = (int)cvt_pk_bf16(acc[mt][nt][2], acc[mt][nt][3]);
        *(i32x2*)(tw + dloc * 64 + phys * 8 + boff) = pr;  // 8B aligned
      }
    }
    // read rows (b128, swizzled) & store 16B runs: vt[bh][d][n0..n0+63]
    const int d = lane;
    uint16_t* vg = vt + (size_t)bh * 131072 + (size_t)d * 2048 + n0;
#pragma unroll
    for (int j = 0; j < 8; ++j) {
      const int phys = j ^ (d & 7);
      const s16x8 r = *(const s16x8*)(tw + d * 64 + phys * 8);
      *(s16x8*)(vg + j * 8) = r;
    }
  } else {
    // Q/K routing: col = which*1024 + h*64 + d -> dst[bh][n][64] (bf16)
    uint16_t* dst = (which == 0) ? rq : rk;
    // Q pre-scaled by log2(e)/sqrt(D): folds softmax scale into the logits.
    const float qs = (which == 0) ? 0.18033688011112042f : 1.0f;
#pragma unroll
    for (int mt = 0; mt < 4; ++mt) {
#pragma unroll
      for (int nt = 0; nt < 4; ++nt) {
        const int colg0 = col0 + wn + nt * 16;
        const int h = (colg0 >> 6) & 15, d0 = colg0 & 63;
#pragma unroll
        for (int i = 0; i < 4; ++i) {
          const int rowg = row0 + wm + mt * 16 + quad * 4 + i;
          const int bh = ((rowg >> 11) << 4) + h, n = rowg & 2047;
          dst[(size_t)bh * 131072 + (size_t)n * 64 + d0 + l15] = f2bf(acc[mt][nt][i] * qs);
        }
      }
    }
  }
}

// ---------------- GEMM2 (m97 BK=64 + swizzle, head-layout A): out = attn @ wprojT^T + bias ----------------
// A lives in q_ws as [bh][n][64]: elem(row,k) = b<<21 | h<<17 | n<<6 | d.
__global__ __launch_bounds__(256) void gemm2_kernel(
    const uint16_t* __restrict__ Aq, const uint16_t* __restrict__ Bt,
    float* __restrict__ Cout, const float* __restrict__ bias) {
  constexpr int N = 1024, K = 1024;
  __shared__ uint16_t sA[128 * 64];
  __shared__ uint16_t sB[128 * 64];
  const int tid = threadIdx.x;
  const int lane = tid & 63, w = tid >> 6;
  const int l15 = lane & 15, quad = lane >> 4;
  const int row0 = blockIdx.y * 128, col0 = blockIdx.x * 128;
  const int wm = (w >> 1) * 64, wn = (w & 1) * 64;

  f32x4 acc[4][4];
#pragma unroll
  for (int i = 0; i < 4; ++i)
#pragma unroll
    for (int j = 0; j < 4; ++j)
#pragma unroll
      for (int e = 0; e < 4; ++e) acc[i][j][e] = 0.0f;

  const int sx = l15 & 7;
  const int ok[2] = {((0 * 4 + quad) ^ sx) * 8, ((1 * 4 + quad) ^ sx) * 8};

  for (int k0 = 0; k0 < K; k0 += 64) {
    __syncthreads();
#pragma unroll
    for (int i = 0; i < 4; ++i) {
      const int cbase = i * 256 + w * 64;  // wave-uniform
      const int c = cbase + lane;
      const int r = c >> 3;
      const int kc = ((c & 7) ^ (r & 7)) * 8;
      const int row = row0 + r, k = k0 + kc;
      const size_t aoff = ((size_t)(row >> 11) << 21) + ((size_t)(k >> 6) << 17) +
                          ((size_t)(row & 2047) << 6) + (size_t)(k & 63);
      GLOAD_LDS16(Aq + aoff, sA + cbase * 8);
      GLOAD_LDS16(Bt + (size_t)(col0 + r) * K + k0 + kc, sB + cbase * 8);
    }
    __syncthreads();

#pragma unroll
    for (int kk = 0; kk < 2; ++kk) {
      s16x8 aF[4], bF[4];
#pragma unroll
      for (int mt = 0; mt < 4; ++mt)
        aF[mt] = *(const s16x8*)(sA + (wm + mt * 16 + l15) * 64 + ok[kk]);
#pragma unroll
      for (int nt = 0; nt < 4; ++nt)
        bF[nt] = *(const s16x8*)(sB + (wn + nt * 16 + l15) * 64 + ok[kk]);
#pragma unroll
      for (int mt = 0; mt < 4; ++mt)
#pragma unroll
        for (int nt = 0; nt < 4; ++nt)
          acc[mt][nt] = __builtin_amdgcn_mfma_f32_16x16x32_bf16(aF[mt], bF[nt], acc[mt][nt], 0, 0, 0);
    }
  }

#pragma unroll
  for (int mt = 0; mt < 4; ++mt) {
#pragma unroll
    for (int nt = 0; nt < 4; ++nt) {
      const int colg = col0 + wn + nt * 16 + l15;
      const float bv = bias[colg];
#pragma unroll
      for (int i = 0; i < 4; ++i) {
        const int rowg = row0 + wm + mt * 16 + quad * 4 + i;
        Cout[(size_t)rowg * N + colg] = acc[mt][nt][i] + bv;
      }
    }
  }
}

// ---------------- Flash attention: both chains pipelined, swizzled LDS ----------------
// Grid (p, bh). Block handles q-tiles p and 31-p: constant 33 tile-computes.
// Q,K: [bh][n][64] (Q pre-scaled); VT: [bh][64][2048]. 4 waves x 16 q-rows/tile.
// Swapped QK^T: S^T = mfma(K_frag, Q_frag) -> lane (l15,quad) holds
// P[q=w*16+l15][kv=nt*16+quad*4+i]. Lane-local k-slot map for PV:
// slot(quad,j) -> kv = kk*32 + (j>=4)*16 + quad*4 + (j&3); aP packs with no
// cross-lane ops; B-frag = two ds_read_b64 from swizzled VT rows (same map).
// LDS: sK/sV [2][64*64] unpadded, 8-elem-chunk XOR swizzle phys=chunk^(row&7).
// Schedule per iter t: [stage buf(t&1); prefetch t+1; finish_H(t-1);
// finish_L(t-1)] | barrier | [qkt_H(t); qkt_L(t)]. L diag finish in-loop.
// OUTPUT: back into q_ws, head layout [bh][n][64] (race-free: block reads only
// its own Q rows, hoisted at start). Row-sum l via mfma(aP, ones).
__global__ __launch_bounds__(256) void attn_kernel(
    const uint16_t* q_ws, const uint16_t* __restrict__ k_ws,
    const uint16_t* __restrict__ vt_ws, uint16_t* outq) {
  const int p = blockIdx.x;  // 0..15
  const int bh = blockIdx.y;
  const int q0L = p * 64, q0H = (31 - p) * 64;
  const int tid = threadIdx.x;
  const int lane = tid & 63, w = tid >> 6;
  const int l15 = lane & 15, quad = lane >> 4;

  const uint16_t* qb = q_ws + (size_t)bh * 131072;
  const uint16_t* kb = k_ws + (size_t)bh * 131072;
  const uint16_t* vtb = vt_ws + (size_t)bh * 131072;

  __shared__ uint16_t sK[2][64 * 64];  // [buf][row][chunk^(row&7)], no pad
  __shared__ uint16_t sV[2][64 * 64];

  const int qrowL = q0L + w * 16 + l15;
  const int qrowH = q0H + w * 16 + l15;
  const s16x8 aQL0 = *(const s16x8*)(qb + (size_t)qrowL * 64 + quad * 8);
  const s16x8 aQL1 = *(const s16x8*)(qb + (size_t)qrowL * 64 + 32 + quad * 8);
  const s16x8 aQH0 = *(const s16x8*)(qb + (size_t)qrowH * 64 + quad * 8);
  const s16x8 aQH1 = *(const s16x8*)(qb + (size_t)qrowH * 64 + 32 + quad * 8);

  f32x4 oL[4], oH[4], laccL, laccH;
#pragma unroll
  for (int e = 0; e < 4; ++e) { laccL[e] = 0.0f; laccH[e] = 0.0f; }
#pragma unroll
  for (int i = 0; i < 4; ++i)
#pragma unroll
    for (int e = 0; e < 4; ++e) { oL[i][e] = 0.0f; oH[i][e] = 0.0f; }

  s16x8 bOnes;
#pragma unroll
  for (int j = 0; j < 8; ++j) bOnes[j] = (short)0x3F80;  // bf16 1.0

  // staging geometry: thread owns row vr, chunks c0=2*(tid&3), c0+1 (16B each)
  const int vr = tid >> 2, dc = (tid & 3) * 16;
  const int wc0 = ((tid & 3) * 2 + 0) ^ (vr & 7);  // swizzled phys chunks
  const int wc1 = ((tid & 3) * 2 + 1) ^ (vr & 7);
  s16x8 rk0 = *(const s16x8*)(kb + (size_t)vr * 64 + dc);
  s16x8 rk1 = *(const s16x8*)(kb + (size_t)vr * 64 + dc + 8);
  s16x8 rv0 = *(const s16x8*)(vtb + (size_t)vr * 2048 + dc);
  s16x8 rv1 = *(const s16x8*)(vtb + (size_t)vr * 2048 + dc + 8);

  // read-side swizzled offsets (lane-constant), rows have (row&7) == (l15&7)
  const int sx = l15 & 7;
  const int okK0 = (quad ^ sx) * 8;        // K chunk quad
  const int okK1 = ((quad + 4) ^ sx) * 8;  // K chunk quad+4
  // V b64 reads: logical chunk kk*4 + (quad>>1) (+2 for upper), in-chunk (quad&1)*4
  const int ovA[2] = {((0 + (quad >> 1)) ^ sx) * 8 + (quad & 1) * 4,
                      ((4 + (quad >> 1)) ^ sx) * 8 + (quad & 1) * 4};
  const int ovB[2] = {((2 + (quad >> 1)) ^ sx) * 8 + (quad & 1) * 4,
                      ((6 + (quad >> 1)) ^ sx) * 8 + (quad & 1) * 4};

  const int qrel = w * 16 + l15;  // q index within 64-row tile

  // QK^T for one q-tile: 8 MFMA, result into s[4] (kept in VGPRs).
  auto qkt = [&](const s16x8& a0, const s16x8& a1, const uint16_t* sKb,
                 f32x4 (&s)[4]) {
#pragma unroll
    for (int nt = 0; nt < 4; ++nt) {
      f32x4 z;
#pragma unroll
      for (int e = 0; e < 4; ++e) z[e] = 0.0f;
      const s16x8 bK0 = *(const s16x8*)(sKb + (nt * 16 + l15) * 64 + okK0);
      const s16x8 bK1 = *(const s16x8*)(sKb + (nt * 16 + l15) * 64 + okK1);
      // swapped operands: A=K rows (kv), B=Q row -> C[kv][q], col q = l15
      s[nt] = __builtin_amdgcn_mfma_f32_16x16x32_bf16(bK0, a0, z, 0, 0, 0);
      s[nt] = __builtin_amdgcn_mfma_f32_16x16x32_bf16(bK1, a1, s[nt], 0, 0, 0);
    }
  };

  // softmax finish (P = exp2(s), raw v_exp_f32) + lane-local pack + lacc + PV.
  // k-slot map: slot(quad,j) -> kv = kk*32 + (j>=4)*16 + quad*4 + (j&3).
  auto finish = [&](const f32x4 (&s)[4], bool diag, f32x4* o, f32x4& lacc,
                    const uint16_t* sVb) {
#pragma unroll
    for (int kk = 0; kk < 2; ++kk) {
      u32 wlo[2], whi[2];
#pragma unroll
      for (int t2 = 0; t2 < 2; ++t2) {
        const f32x4& sv = s[2 * kk + t2];
        float pp[4];
        if (diag) {
          const int nt = 2 * kk + t2;
#pragma unroll
          for (int i = 0; i < 4; ++i) {
            const int kv = nt * 16 + quad * 4 + i;
            pp[i] = (kv > qrel) ? 0.0f : __builtin_amdgcn_exp2f(sv[i]);
          }
        } else {
#pragma unroll
          for (int i = 0; i < 4; ++i) pp[i] = __builtin_amdgcn_exp2f(sv[i]);
        }
        wlo[t2] = cvt_pk_bf16(pp[0], pp[1]);  // kv +0,+1
        whi[t2] = cvt_pk_bf16(pp[2], pp[3]);  // kv +2,+3
      }
      // lane-local A-frag: j0..3 = nt=2kk (kv=kk*32+quad*4+j),
      //                    j4..7 = nt=2kk+1 (kv=kk*32+16+quad*4+j)
      const s16x8 aP = pack4(wlo[0], whi[0], wlo[1], whi[1]);
      // row-sum l via matrix pipe (ones operand: slot-map-invariant)
      lacc = __builtin_amdgcn_mfma_f32_16x16x32_bf16(aP, bOnes, lacc, 0, 0, 0);
#pragma unroll
      for (int dblk = 0; dblk < 4; ++dblk) {
        const uint16_t* vrow = sVb + (dblk * 16 + l15) * 64;
        const s16x4 b0 = *(const s16x4*)(vrow + ovA[kk]);  // kv kk*32+quad*4+..
        const s16x4 b1 = *(const s16x4*)(vrow + ovB[kk]);  // kv kk*32+16+quad*4+..
        const s16x8 bV = pack2h(b0, b1);
        o[dblk] = __builtin_amdgcn_mfma_f32_16x16x32_bf16(aP, bV, o[dblk], 0, 0, 0);
      }
    }
  };

  const int TH = q0H >> 6;  // last H tile (diag), = 31-p >= 16
  const int TL = q0L >> 6;  // last L tile (diag), = p <= 15 < TH
  f32x4 sHp[4], sLp[4];     // carried QK^T results for both pipelines

  for (int t = 0; t <= TH; ++t) {
    const int buf = t & 1;
    uint16_t* sKb = sK[buf];
    uint16_t* sVb = sV[buf];
    // stage current tile's K/V (regs loaded prev iter) -> swizzled chunks
    *(s16x8*)(sKb + vr * 64 + wc0 * 8) = rk0;
    *(s16x8*)(sKb + vr * 64 + wc1 * 8) = rk1;
    *(s16x8*)(sVb + vr * 64 + wc0 * 8) = rv0;
    *(s16x8*)(sVb + vr * 64 + wc1 * 8) = rv1;
    // prefetch next tile
    if (t < TH) {
      const int kvn = (t + 1) << 6;
      rk0 = *(const s16x8*)(kb + (size_t)(kvn + vr) * 64 + dc);
      rk1 = *(const s16x8*)(kb + (size_t)(kvn + vr) * 64 + dc + 8);
      rv0 = *(const s16x8*)(vtb + (size_t)vr * 2048 + kvn + dc);
      rv1 = *(const s16x8*)(vtb + (size_t)vr * 2048 + kvn + dc + 8);
    }
    // finish previous tiles (read sV[buf^1] = tile t-1; safe pre-barrier:
    // all waves complete these reads before barrier t, which precedes the
    // overwrite of that buffer at iteration t+1).
    if (t >= 1) {
      finish(sHp, false, oH, laccH, sV[buf ^ 1]);  // H diag -> epilogue
      if (t - 1 <= TL) finish(sLp, (t - 1) == TL, oL, laccL, sV[buf ^ 1]);
    }
    __syncthreads();
    // QK^T current tiles (consumed by next iteration's finishes)
    qkt(aQH0, aQH1, sKb, sHp);
    if (t <= TL) qkt(aQL0, aQL1, sKb, sLp);
  }
  finish(sHp, true, oH, laccH, sV[TH & 1]);  // epilogue: diag H tile

  // epilogue -> head layout [bh][row][64] over q_ws (own rows only: race-free)
  uint16_t* ob = outq + (size_t)bh * 131072;
  auto epi = [&](f32x4* o, const f32x4& lacc, int q0) {
#pragma unroll
    for (int i = 0; i < 4; ++i) {
      const float invi = 1.0f / lacc[i];  // sum for q-row quad*4+i (C layout)
      const int row = q0 + w * 16 + quad * 4 + i;
#pragma unroll
      for (int dblk = 0; dblk < 4; ++dblk)
        ob[(size_t)row * 64 + dblk * 16 + l15] = f2bf(o[dblk][i] * invi);
    }
  };
  epi(oH, laccH, q0H);
  epi(oL, laccL, q0L);
}

extern "C" void kernel_launch(void* const* d_in, const int* in_sizes, int n_in,
                              void* d_out, int out_size, void* d_ws, size_t ws_size,
                              hipStream_t stream) {
  (void)in_sizes; (void)n_in; (void)out_size; (void)ws_size;
  const float* x     = (const float*)d_in[0];
  // d_in[1] = attn_mask: exactly causal, applied analytically
  const float* Wqkv  = (const float*)d_in[2];
  const float* Wproj = (const float*)d_in[3];
  const float* bproj = (const float*)d_in[4];
  float* outp = (float*)d_out;

  uint16_t* ws      = (uint16_t*)d_ws;
  uint16_t* q_ws    = ws;                        // q in, attn out (head layout)
  uint16_t* k_ws    = ws + (size_t)8388608;
  uint16_t* vt_ws   = ws + (size_t)16777216;     // VT, written by gemm1
  uint16_t* wqkvT   = ws + (size_t)25165824;     // 3.1M u16, GEMM1 B operand
  uint16_t* wprojT  = ws + (size_t)28311552;     // 1.0M u16, written in prep
  uint16_t* xbf     = (uint16_t*)d_out;          // d_out scratch; dead after GEMM1

  // prep: blocks [0,4096) cvt, [4096,7168) tWqkv, [7168,8192) tWproj
  prep_kernel<<<8192, 256, 0, stream>>>(x, xbf, Wqkv, wqkvT, Wproj, wprojT);
  gemm1_kernel<<<dim3(24, 64), 256, 0, stream>>>(xbf, wqkvT, q_ws, k_ws, vt_ws);
  attn_kernel<<<dim3(16, 64), 256, 0, stream>>>(q_ws, k_ws, vt_ws, q_ws);
  gemm2_kernel<<<dim3(8, 64), 256, 0, stream>>>(q_ws, wprojT, outp, bproj);
}